// Round 5
// baseline (1010.489 us; speedup 1.0000x reference)
//
#include <hip/hip_runtime.h>
#include <hip/hip_bf16.h>

#define N_NODES 50000
#define N_EDGES 800000

// K1: el1/er1 per (node,head). feat computed transiently, NOT stored.
__global__ __launch_bounds__(256) void k_el_er(const float* __restrict__ x,
    const float* __restrict__ W1, const float* __restrict__ al1, const float* __restrict__ ar1,
    float* __restrict__ el1, float* __restrict__ er1) {
  int n = blockIdx.x, t = threadIdx.x;
  __shared__ float xs[64];
  __shared__ float redl[256], redr[256];
  if (t < 64) xs[t] = x[n * 64 + t];
  __syncthreads();
  float acc = 0.f;
#pragma unroll
  for (int k = 0; k < 64; ++k) acc += xs[k] * W1[k * 256 + t];
  redl[t] = acc * al1[t];
  redr[t] = acc * ar1[t];
  __syncthreads();
  for (int off = 16; off > 0; off >>= 1) {
    if ((t & 31) < off) {
      redl[t] += redl[t + off];
      redr[t] += redr[t + off];
    }
    __syncthreads();
  }
  if ((t & 31) == 0) {
    el1[n * 8 + (t >> 5)] = redl[t];
    er1[n * 8 + (t >> 5)] = redr[t];
  }
}

// K2: s1[dst,h] += exp(leaky(el[src,h]+er[dst,h]))
__global__ __launch_bounds__(256) void k_s1(const int* __restrict__ src,
    const int* __restrict__ dst, const float* __restrict__ el1, const float* __restrict__ er1,
    float* __restrict__ s1) {
  int idx = blockIdx.x * 256 + threadIdx.x;  // < E*8
  int e = idx >> 3, h = idx & 7;
  int sN = src[e], dN = dst[e];
  float v = el1[sN * 8 + h] + er1[dN * 8 + h];
  v = v > 0.f ? v : 0.2f * v;
  unsafeAtomicAdd(&s1[dN * 8 + h], __expf(v));
}

// K3: out1[dst,t] += feat(src,t)*alpha(e,h), feat recomputed: W1 column in regs,
// 64 edges' x-rows staged in LDS. Grid: 12500 blocks x 64 edges.
__global__ __launch_bounds__(256) void k_agg1_rc(const float* __restrict__ x,
    const float* __restrict__ W1, const int* __restrict__ src, const int* __restrict__ dst,
    const float* __restrict__ el1, const float* __restrict__ er1,
    const float* __restrict__ s1, float* __restrict__ out1) {
  int t = threadIdx.x;
  int e0 = blockIdx.x * 64;
  __shared__ float xs_all[64][64];   // 16 KB
  __shared__ float alpha_ls[64][8];  // 2 KB
  __shared__ int sn_ls[64], dn_ls[64];
  // W1 column t -> registers
  float w[64];
#pragma unroll
  for (int k = 0; k < 64; ++k) w[k] = W1[k * 256 + t];
  if (t < 64) { sn_ls[t] = src[e0 + t]; dn_ls[t] = dst[e0 + t]; }
  __syncthreads();
  // stage x rows of the 64 src nodes
  {
    int j = t & 63, ib = t >> 6;
#pragma unroll
    for (int r = 0; r < 16; ++r) {
      int i = r * 4 + ib;
      xs_all[i][j] = x[sn_ls[i] * 64 + j];
    }
  }
  // alphas for 64 edges x 8 heads
  for (int p = t; p < 512; p += 256) {
    int i = p >> 3, h = p & 7;
    int sN = sn_ls[i], dN = dn_ls[i];
    float v = el1[sN * 8 + h] + er1[dN * 8 + h];
    v = v > 0.f ? v : 0.2f * v;
    alpha_ls[i][h] = __expf(v) / s1[dN * 8 + h];
  }
  __syncthreads();
  int h = t >> 5;
  for (int i = 0; i < 64; ++i) {
    float acc = 0.f;
#pragma unroll
    for (int k = 0; k < 64; ++k) acc += xs_all[i][k] * w[k];
    unsafeAtomicAdd(&out1[dn_ls[i] * 256 + t], acc * alpha_ls[i][h]);
  }
}

// K4: h = relu(out1 + b1); feat2[n] = h . W2; el2/er2 scalars.
__global__ __launch_bounds__(256) void k_layer2_feat(const float* __restrict__ out1,
    const float* __restrict__ b1, const float* __restrict__ W2, const float* __restrict__ al2,
    const float* __restrict__ ar2, float* __restrict__ feat2, float* __restrict__ el2,
    float* __restrict__ er2) {
  int n = blockIdx.x, t = threadIdx.x;
  __shared__ float red[256];
  float v = out1[n * 256 + t] + b1[t];
  v = fmaxf(v, 0.f);
  red[t] = v * W2[t];
  __syncthreads();
  for (int off = 128; off > 0; off >>= 1) {
    if (t < off) red[t] += red[t + off];
    __syncthreads();
  }
  if (t == 0) {
    float f = red[0];
    feat2[n] = f;
    el2[n] = f * al2[0];
    er2[n] = f * ar2[0];
  }
}

// K5: s2[dst] += exp(leaky(el2[src]+er2[dst]))
__global__ __launch_bounds__(256) void k_s2(const int* __restrict__ src,
    const int* __restrict__ dst, const float* __restrict__ el2, const float* __restrict__ er2,
    float* __restrict__ s2) {
  int e = blockIdx.x * 256 + threadIdx.x;
  float v = el2[src[e]] + er2[dst[e]];
  v = v > 0.f ? v : 0.2f * v;
  unsafeAtomicAdd(&s2[dst[e]], __expf(v));
}

// K6: out2[dst] += feat2[src] * exp(leaky(...))/s2[dst]
__global__ __launch_bounds__(256) void k_agg2(const int* __restrict__ src,
    const int* __restrict__ dst, const float* __restrict__ feat2,
    const float* __restrict__ el2, const float* __restrict__ er2,
    const float* __restrict__ s2, float* __restrict__ out2) {
  int e = blockIdx.x * 256 + threadIdx.x;
  int sN = src[e], dN = dst[e];
  float v = el2[sN] + er2[dN];
  v = v > 0.f ? v : 0.2f * v;
  unsafeAtomicAdd(&out2[dN], feat2[sN] * __expf(v) / s2[dN]);
}

// K7: out[n] = sigmoid(out2[n] + b2)  — fp32 output
__global__ __launch_bounds__(256) void k_final(const float* __restrict__ out2,
    const float* __restrict__ b2, float* __restrict__ out) {
  int n = blockIdx.x * 256 + threadIdx.x;
  if (n < N_NODES) {
    float v = out2[n] + b2[0];
    out[n] = 1.f / (1.f + __expf(-v));
  }
}

extern "C" void kernel_launch(void* const* d_in, const int* in_sizes, int n_in,
                              void* d_out, int out_size, void* d_ws, size_t ws_size,
                              hipStream_t stream) {
  const float* x   = (const float*)d_in[0];
  const int* src   = (const int*)d_in[1];
  const int* dst   = (const int*)d_in[2];
  // d_in[3] = edge_types (unused by reference)
  const float* W1  = (const float*)d_in[4];
  const float* al1 = (const float*)d_in[5];
  const float* ar1 = (const float*)d_in[6];
  const float* b1  = (const float*)d_in[7];
  const float* W2  = (const float*)d_in[8];
  const float* al2 = (const float*)d_in[9];
  const float* ar2 = (const float*)d_in[10];
  const float* b2  = (const float*)d_in[11];

  // Slim workspace: 14.25M floats = 57.0 MB total.
  float* ws    = (float*)d_ws;
  float* el1   = ws;                 //    400,000
  float* er1   = el1 + 400000;       //    400,000
  float* feat2 = er1 + 400000;       //     50,000
  float* el2   = feat2 + 50000;      //     50,000
  float* er2   = el2 + 50000;        //     50,000
  // contiguous zero-init region:
  float* s1    = er2 + 50000;        //    400,000
  float* out1  = s1 + 400000;        // 12,800,000
  float* s2    = out1 + 12800000;    //     50,000
  float* out2  = s2 + 50000;         //     50,000

  hipMemsetAsync(s1, 0, (size_t)(400000 + 12800000 + 50000 + 50000) * sizeof(float), stream);

  k_el_er<<<N_NODES, 256, 0, stream>>>(x, W1, al1, ar1, el1, er1);
  k_s1<<<(N_EDGES * 8) / 256, 256, 0, stream>>>(src, dst, el1, er1, s1);
  k_agg1_rc<<<N_EDGES / 64, 256, 0, stream>>>(x, W1, src, dst, el1, er1, s1, out1);
  k_layer2_feat<<<N_NODES, 256, 0, stream>>>(out1, b1, W2, al2, ar2, feat2, el2, er2);
  k_s2<<<N_EDGES / 256, 256, 0, stream>>>(src, dst, el2, er2, s2);
  k_agg2<<<N_EDGES / 256, 256, 0, stream>>>(src, dst, feat2, el2, er2, s2, out2);
  k_final<<<(N_NODES + 255) / 256, 256, 0, stream>>>(out2, b2, (float*)d_out);
}

// Round 6
// 585.902 us; speedup vs baseline: 1.7247x; 1.7247x over previous
//
#include <hip/hip_runtime.h>

#define N_NODES 50000
#define N_EDGES 800000

// ---- CSR construction ----
__global__ __launch_bounds__(256) void k_deg(const int* __restrict__ dst, int* __restrict__ deg) {
  int e = blockIdx.x * 256 + threadIdx.x;
  if (e < N_EDGES) atomicAdd(&deg[dst[e]], 1);
}

// single block, 1024 threads: exclusive prefix sum over deg -> row_ptr, cursor
__global__ __launch_bounds__(1024) void k_scan(const int* __restrict__ deg,
    int* __restrict__ row_ptr, int* __restrict__ cursor) {
  __shared__ int part[1024];
  int t = threadIdx.x;
  const int C = (N_NODES + 1023) / 1024;  // 49
  int base = t * C;
  int local = 0;
  for (int i = 0; i < C; ++i) {
    int idx = base + i;
    if (idx < N_NODES) local += deg[idx];
  }
  part[t] = local;
  __syncthreads();
  for (int off = 1; off < 1024; off <<= 1) {
    int v = (t >= off) ? part[t - off] : 0;
    __syncthreads();
    part[t] += v;
    __syncthreads();
  }
  int run = (t == 0) ? 0 : part[t - 1];
  for (int i = 0; i < C; ++i) {
    int idx = base + i;
    if (idx < N_NODES) {
      row_ptr[idx] = run;
      cursor[idx] = run;
      run += deg[idx];
    }
  }
  if (t == 1023) row_ptr[N_NODES] = run;  // = N_EDGES
}

__global__ __launch_bounds__(256) void k_scatter(const int* __restrict__ src,
    const int* __restrict__ dst, int* __restrict__ cursor, int* __restrict__ esrc) {
  int e = blockIdx.x * 256 + threadIdx.x;
  if (e < N_EDGES) {
    int p = atomicAdd(&cursor[dst[e]], 1);
    esrc[p] = src[e];
  }
}

// ---- feat1 = x @ W1 : 16 nodes/block, W1 column in registers ----
__global__ __launch_bounds__(256) void k_feat(const float* __restrict__ x,
    const float* __restrict__ W1, float* __restrict__ feat1) {
  int t = threadIdx.x;
  int n0 = blockIdx.x * 16;
  __shared__ float xs[16][64];
  float w[64];
#pragma unroll
  for (int k = 0; k < 64; ++k) w[k] = W1[k * 256 + t];
#pragma unroll
  for (int r = 0; r < 4; ++r) {
    int p = r * 256 + t;
    xs[p >> 6][p & 63] = x[n0 * 64 + p];
  }
  __syncthreads();
#pragma unroll
  for (int i = 0; i < 16; ++i) {
    float acc = 0.f;
#pragma unroll
    for (int k = 0; k < 64; ++k) acc += xs[i][k] * w[k];
    feat1[(n0 + i) * 256 + t] = acc;
  }
}

// ---- el1/er1 from feat1 ----
__global__ __launch_bounds__(256) void k_el_er(const float* __restrict__ feat1,
    const float* __restrict__ al1, const float* __restrict__ ar1,
    float* __restrict__ el1, float* __restrict__ er1) {
  int n = blockIdx.x, t = threadIdx.x;
  __shared__ float redl[256], redr[256];
  float f = feat1[n * 256 + t];
  redl[t] = f * al1[t];
  redr[t] = f * ar1[t];
  __syncthreads();
  for (int off = 16; off > 0; off >>= 1) {
    if ((t & 31) < off) { redl[t] += redl[t + off]; redr[t] += redr[t + off]; }
    __syncthreads();
  }
  if ((t & 31) == 0) { el1[n * 8 + (t >> 5)] = redl[t]; er1[n * 8 + (t >> 5)] = redr[t]; }
}

// ---- layer-1 aggregation, fully fused: num & s in one pass, epilogue ReLU+W2 ----
__global__ __launch_bounds__(256) void k_agg1(const int* __restrict__ row_ptr,
    const int* __restrict__ esrc, const float* __restrict__ feat1,
    const float* __restrict__ el1, const float* __restrict__ er1,
    const float* __restrict__ b1, const float* __restrict__ W2,
    const float* __restrict__ al2, const float* __restrict__ ar2,
    float* __restrict__ feat2, float* __restrict__ el2, float* __restrict__ er2) {
  int n = blockIdx.x, t = threadIdx.x, h = t >> 5;
  int begin = row_ptr[n], end = row_ptr[n + 1];
  float er_h = er1[n * 8 + h];
  float num = 0.f, s = 0.f;
  for (int e = begin; e < end; ++e) {
    int sN = esrc[e];
    float v = el1[sN * 8 + h] + er_h;
    v = v > 0.f ? v : 0.2f * v;
    float ex = __expf(v);
    num += feat1[sN * 256 + t] * ex;
    s += ex;
  }
  float val = (end > begin) ? num / s : 0.f;  // out1[n,t] (pre-bias)
  float v2 = fmaxf(val + b1[t], 0.f);         // relu(out1 + b1)
  __shared__ float red[256];
  red[t] = v2 * W2[t];
  __syncthreads();
  for (int off = 128; off > 0; off >>= 1) {
    if (t < off) red[t] += red[t + off];
    __syncthreads();
  }
  if (t == 0) {
    float f = red[0];
    feat2[n] = f;
    el2[n] = f * al2[0];
    er2[n] = f * ar2[0];
  }
}

// ---- layer-2 fused: s2 + aggregation + sigmoid, one wave per node ----
__global__ __launch_bounds__(64) void k_layer2(const int* __restrict__ row_ptr,
    const int* __restrict__ esrc, const float* __restrict__ feat2,
    const float* __restrict__ el2, const float* __restrict__ er2,
    const float* __restrict__ b2, float* __restrict__ out) {
  int n = blockIdx.x, t = threadIdx.x;
  int begin = row_ptr[n], end = row_ptr[n + 1];
  float er_n = er2[n];
  float num = 0.f, s = 0.f;
  for (int e = begin + t; e < end; e += 64) {
    int sN = esrc[e];
    float v = el2[sN] + er_n;
    v = v > 0.f ? v : 0.2f * v;
    float ex = __expf(v);
    num += feat2[sN] * ex;
    s += ex;
  }
  __shared__ float rn[64], rs[64];
  rn[t] = num; rs[t] = s;
  __syncthreads();
  for (int off = 32; off > 0; off >>= 1) {
    if (t < off) { rn[t] += rn[t + off]; rs[t] += rs[t + off]; }
    __syncthreads();
  }
  if (t == 0) {
    float val = (end > begin) ? rn[0] / rs[0] : 0.f;
    out[n] = 1.f / (1.f + __expf(-(val + b2[0])));
  }
}

extern "C" void kernel_launch(void* const* d_in, const int* in_sizes, int n_in,
                              void* d_out, int out_size, void* d_ws, size_t ws_size,
                              hipStream_t stream) {
  const float* x   = (const float*)d_in[0];
  const int* src   = (const int*)d_in[1];
  const int* dst   = (const int*)d_in[2];
  // d_in[3] = edge_types (unused by reference)
  const float* W1  = (const float*)d_in[4];
  const float* al1 = (const float*)d_in[5];
  const float* ar1 = (const float*)d_in[6];
  const float* b1  = (const float*)d_in[7];
  const float* W2  = (const float*)d_in[8];
  const float* al2 = (const float*)d_in[9];
  const float* ar2 = (const float*)d_in[10];
  const float* b2  = (const float*)d_in[11];

  // Workspace: ~58.8 MB
  float* ws    = (float*)d_ws;
  float* feat1 = ws;                   // 12,800,000 f
  float* el1   = feat1 + 12800000;     //    400,000 f
  float* er1   = el1 + 400000;         //    400,000 f
  float* feat2 = er1 + 400000;         //     50,000 f
  float* el2   = feat2 + 50000;        //     50,000 f
  float* er2   = el2 + 50000;          //     50,000 f
  int* row_ptr = (int*)(er2 + 50000);  //     50,001 i
  int* deg     = row_ptr + 50001;      //     50,000 i (zero-init)
  int* cursor  = deg + 50000;          //     50,000 i
  int* esrc    = cursor + 50000;       //    800,000 i

  hipMemsetAsync(deg, 0, 50000 * sizeof(int), stream);

  k_deg<<<N_EDGES / 256, 256, 0, stream>>>(dst, deg);
  k_scan<<<1, 1024, 0, stream>>>(deg, row_ptr, cursor);
  k_scatter<<<N_EDGES / 256, 256, 0, stream>>>(src, dst, cursor, esrc);
  k_feat<<<N_NODES / 16, 256, 0, stream>>>(x, W1, feat1);
  k_el_er<<<N_NODES, 256, 0, stream>>>(feat1, al1, ar1, el1, er1);
  k_agg1<<<N_NODES, 256, 0, stream>>>(row_ptr, esrc, feat1, el1, er1, b1, W2, al2, ar2,
                                      feat2, el2, er2);
  k_layer2<<<N_NODES, 64, 0, stream>>>(row_ptr, esrc, feat2, el2, er2, b2, (float*)d_out);
}

// Round 7
// 538.787 us; speedup vs baseline: 1.8755x; 1.0874x over previous
//
#include <hip/hip_runtime.h>

#define N_NODES 50000
#define N_EDGES 800000

typedef unsigned int uint32;
typedef unsigned short ushort16;

// fp32 -> bf16 bits, round-to-nearest-even
__device__ __forceinline__ ushort16 f2bf(float f) {
  uint32 u = __float_as_uint(f);
  u += 0x7fffu + ((u >> 16) & 1u);
  return (ushort16)(u >> 16);
}

// ---- CSR construction ----
__global__ __launch_bounds__(256) void k_deg(const int* __restrict__ dst, int* __restrict__ deg) {
  int e = blockIdx.x * 256 + threadIdx.x;
  if (e < N_EDGES) atomicAdd(&deg[dst[e]], 1);
}

__global__ __launch_bounds__(1024) void k_scan(const int* __restrict__ deg,
    int* __restrict__ row_ptr, int* __restrict__ cursor) {
  __shared__ int part[1024];
  int t = threadIdx.x;
  const int C = (N_NODES + 1023) / 1024;  // 49
  int base = t * C;
  int local = 0;
  for (int i = 0; i < C; ++i) {
    int idx = base + i;
    if (idx < N_NODES) local += deg[idx];
  }
  part[t] = local;
  __syncthreads();
  for (int off = 1; off < 1024; off <<= 1) {
    int v = (t >= off) ? part[t - off] : 0;
    __syncthreads();
    part[t] += v;
    __syncthreads();
  }
  int run = (t == 0) ? 0 : part[t - 1];
  for (int i = 0; i < C; ++i) {
    int idx = base + i;
    if (idx < N_NODES) {
      row_ptr[idx] = run;
      cursor[idx] = run;
      run += deg[idx];
    }
  }
  if (t == 1023) row_ptr[N_NODES] = run;
}

__global__ __launch_bounds__(256) void k_scatter(const int* __restrict__ src,
    const int* __restrict__ dst, int* __restrict__ cursor, int* __restrict__ esrc) {
  int e = blockIdx.x * 256 + threadIdx.x;
  if (e < N_EDGES) {
    int p = atomicAdd(&cursor[dst[e]], 1);
    esrc[p] = src[e];
  }
}

// ---- feat1(bf16) = x @ W1, fused el1/er1 (shfl-32 head reductions) ----
__global__ __launch_bounds__(256) void k_feat(const float* __restrict__ x,
    const float* __restrict__ W1, const float* __restrict__ al1, const float* __restrict__ ar1,
    ushort16* __restrict__ feat1b, float* __restrict__ el1, float* __restrict__ er1) {
  int t = threadIdx.x;
  int n0 = blockIdx.x * 16;
  __shared__ float xs[16][64];
  float w[64];
#pragma unroll
  for (int k = 0; k < 64; ++k) w[k] = W1[k * 256 + t];
#pragma unroll
  for (int r = 0; r < 4; ++r) {
    int p = r * 256 + t;
    xs[p >> 6][p & 63] = x[n0 * 64 + p];
  }
  __syncthreads();
  float a_l = al1[t], a_r = ar1[t];
  int h = t >> 5;
#pragma unroll
  for (int i = 0; i < 16; ++i) {
    float acc = 0.f;
#pragma unroll
    for (int k = 0; k < 64; ++k) acc += xs[i][k] * w[k];
    feat1b[(n0 + i) * 256 + t] = f2bf(acc);
    float pl = acc * a_l, pr = acc * a_r;
#pragma unroll
    for (int off = 16; off > 0; off >>= 1) {
      pl += __shfl_down(pl, off, 32);
      pr += __shfl_down(pr, off, 32);
    }
    if ((t & 31) == 0) {
      el1[(n0 + i) * 8 + h] = pl;
      er1[(n0 + i) * 8 + h] = pr;
    }
  }
}

// ---- layer-1 aggregation: 2 nodes/block, 128 thr/node, 2 elems/thr (4B loads),
// fused softmax (num & s one pass) + ReLU + b1 + W2 epilogue ----
__global__ __launch_bounds__(256) void k_agg1(const int* __restrict__ row_ptr,
    const int* __restrict__ esrc, const uint32* __restrict__ feat1b2,
    const float* __restrict__ el1, const float* __restrict__ er1,
    const float* __restrict__ b1, const float* __restrict__ W2,
    const float* __restrict__ al2, const float* __restrict__ ar2,
    float* __restrict__ feat2, float* __restrict__ el2, float* __restrict__ er2) {
  int t = threadIdx.x, tt = t & 127, nl = t >> 7;
  int n = blockIdx.x * 2 + nl;
  int h = tt >> 4;  // element pair (2tt, 2tt+1) -> head (2tt)>>5
  int begin = row_ptr[n], end = row_ptr[n + 1];
  float er_h = er1[n * 8 + h];
  float num0 = 0.f, num1 = 0.f, s = 0.f;
  for (int e = begin; e < end; ++e) {
    int sN = esrc[e];
    uint32 u = feat1b2[sN * 128 + tt];
    float f0 = __uint_as_float(u << 16);
    float f1 = __uint_as_float(u & 0xffff0000u);
    float v = el1[sN * 8 + h] + er_h;
    v = v > 0.f ? v : 0.2f * v;
    float ex = __expf(v);
    num0 += f0 * ex;
    num1 += f1 * ex;
    s += ex;
  }
  float inv = (end > begin) ? 1.f / s : 0.f;
  int o0 = 2 * tt, o1 = o0 + 1;
  float v0 = fmaxf(num0 * inv + b1[o0], 0.f) * W2[o0];
  float v1 = fmaxf(num1 * inv + b1[o1], 0.f) * W2[o1];
  __shared__ float red[256];
  red[t] = v0 + v1;
  __syncthreads();
  for (int off = 64; off > 0; off >>= 1) {
    if (tt < off) red[t] += red[t + off];
    __syncthreads();
  }
  if (tt == 0) {
    float f = red[t];
    feat2[n] = f;
    el2[n] = f * al2[0];
    er2[n] = f * ar2[0];
  }
}

// ---- layer-2 fused: 16 nodes/block, 16 thr/node, shfl-16 reduce, sigmoid ----
__global__ __launch_bounds__(256) void k_layer2(const int* __restrict__ row_ptr,
    const int* __restrict__ esrc, const float* __restrict__ feat2,
    const float* __restrict__ el2, const float* __restrict__ er2,
    const float* __restrict__ b2, float* __restrict__ out) {
  int t = threadIdx.x, g = t >> 4, lt = t & 15;
  int n = blockIdx.x * 16 + g;
  int begin = row_ptr[n], end = row_ptr[n + 1];
  float er_n = er2[n];
  float num = 0.f, s = 0.f;
  for (int e = begin + lt; e < end; e += 16) {
    int sN = esrc[e];
    float v = el2[sN] + er_n;
    v = v > 0.f ? v : 0.2f * v;
    float ex = __expf(v);
    num += feat2[sN] * ex;
    s += ex;
  }
#pragma unroll
  for (int off = 8; off > 0; off >>= 1) {
    num += __shfl_down(num, off, 16);
    s += __shfl_down(s, off, 16);
  }
  if (lt == 0) {
    float val = (end > begin) ? num / s : 0.f;
    out[n] = 1.f / (1.f + __expf(-(val + b2[0])));
  }
}

extern "C" void kernel_launch(void* const* d_in, const int* in_sizes, int n_in,
                              void* d_out, int out_size, void* d_ws, size_t ws_size,
                              hipStream_t stream) {
  const float* x   = (const float*)d_in[0];
  const int* src   = (const int*)d_in[1];
  const int* dst   = (const int*)d_in[2];
  // d_in[3] = edge_types (unused by reference)
  const float* W1  = (const float*)d_in[4];
  const float* al1 = (const float*)d_in[5];
  const float* ar1 = (const float*)d_in[6];
  const float* b1  = (const float*)d_in[7];
  const float* W2  = (const float*)d_in[8];
  const float* al2 = (const float*)d_in[9];
  const float* ar2 = (const float*)d_in[10];
  const float* b2  = (const float*)d_in[11];

  // Workspace ~33 MB
  float* ws    = (float*)d_ws;
  float* el1   = ws;                   //    400,000 f
  float* er1   = el1 + 400000;         //    400,000 f
  float* feat2 = er1 + 400000;         //     50,000 f
  float* el2   = feat2 + 50000;        //     50,000 f
  float* er2   = el2 + 50000;          //     50,000 f
  int* row_ptr = (int*)(er2 + 50000);  //     50,001 i
  int* deg     = row_ptr + 50001;      //     50,000 i (zero-init)
  int* cursor  = deg + 50000;          //     50,000 i
  int* esrc    = cursor + 50000;       //    800,000 i
  ushort16* feat1b = (ushort16*)(esrc + 800000);  // 12,800,000 bf16 (4B-aligned)

  hipMemsetAsync(deg, 0, 50000 * sizeof(int), stream);

  k_deg<<<N_EDGES / 256, 256, 0, stream>>>(dst, deg);
  k_scan<<<1, 1024, 0, stream>>>(deg, row_ptr, cursor);
  k_scatter<<<N_EDGES / 256, 256, 0, stream>>>(src, dst, cursor, esrc);
  k_feat<<<N_NODES / 16, 256, 0, stream>>>(x, W1, al1, ar1, feat1b, el1, er1);
  k_agg1<<<N_NODES / 2, 256, 0, stream>>>(row_ptr, esrc, (const uint32*)feat1b,
                                          el1, er1, b1, W2, al2, ar2, feat2, el2, er2);
  k_layer2<<<N_NODES / 16, 256, 0, stream>>>(row_ptr, esrc, feat2, el2, er2, b2,
                                             (float*)d_out);
}

// Round 9
// 411.495 us; speedup vs baseline: 2.4557x; 1.3093x over previous
//
#include <hip/hip_runtime.h>

#define N_NODES 50000
#define N_EDGES 800000

typedef unsigned int uint32;
typedef unsigned short ushort16;
typedef short bf8v __attribute__((ext_vector_type(8)));   // 8 bf16 (4 VGPRs)
typedef float f32x4 __attribute__((ext_vector_type(4)));

// fp32 -> bf16 bits, round-to-nearest-even (identity on bf16-grid values)
__device__ __forceinline__ ushort16 f2bf(float f) {
  uint32 u = __float_as_uint(f);
  u += 0x7fffu + ((u >> 16) & 1u);
  return (ushort16)(u >> 16);
}

// ---- CSR construction ----
__global__ __launch_bounds__(256) void k_deg(const int* __restrict__ dst, int* __restrict__ deg) {
  int e = blockIdx.x * 256 + threadIdx.x;
  if (e < N_EDGES) atomicAdd(&deg[dst[e]], 1);
}

__global__ __launch_bounds__(1024) void k_scan(const int* __restrict__ deg,
    int* __restrict__ row_ptr, int* __restrict__ cursor) {
  __shared__ int part[1024];
  int t = threadIdx.x;
  const int C = (N_NODES + 1023) / 1024;  // 49
  int base = t * C;
  int local = 0;
  for (int i = 0; i < C; ++i) {
    int idx = base + i;
    if (idx < N_NODES) local += deg[idx];
  }
  part[t] = local;
  __syncthreads();
  for (int off = 1; off < 1024; off <<= 1) {
    int v = (t >= off) ? part[t - off] : 0;
    __syncthreads();
    part[t] += v;
    __syncthreads();
  }
  int run = (t == 0) ? 0 : part[t - 1];
  for (int i = 0; i < C; ++i) {
    int idx = base + i;
    if (idx < N_NODES) {
      row_ptr[idx] = run;
      cursor[idx] = run;
      run += deg[idx];
    }
  }
  if (t == 1023) row_ptr[N_NODES] = run;
}

__global__ __launch_bounds__(256) void k_scatter(const int* __restrict__ src,
    const int* __restrict__ dst, int* __restrict__ cursor, int* __restrict__ esrc) {
  int e = blockIdx.x * 256 + threadIdx.x;
  if (e < N_EDGES) {
    int p = atomicAdd(&cursor[dst[e]], 1);
    esrc[p] = src[e];
  }
}

// ---- x (fp32, bf16-grid) -> bf16 bits; 4 elems/thread ----
__global__ __launch_bounds__(256) void k_cvt_x(const float* __restrict__ x,
    ushort16* __restrict__ xb) {
  int i = (blockIdx.x * 256 + threadIdx.x) * 4;
  float4 v = *(const float4*)(x + i);
  uint32 lo = (uint32)f2bf(v.x) | ((uint32)f2bf(v.y) << 16);
  uint32 hi = (uint32)f2bf(v.z) | ((uint32)f2bf(v.w) << 16);
  *(uint2*)(xb + i) = make_uint2(lo, hi);
}

// ---- W1[64][256] -> W1T bf16 [256][64] ----
__global__ __launch_bounds__(256) void k_cvt_w1t(const float* __restrict__ W1,
    ushort16* __restrict__ w1t) {
  int t = threadIdx.x;  // = column
  for (int k = 0; k < 64; ++k) w1t[t * 64 + k] = f2bf(W1[k * 256 + t]);
}

// ---- feat1b = x @ W1 via MFMA 16x16x32 bf16. Block: 16 nodes x 256 cols, 4 waves.
// A layout: A[m=lane&15][k=quad*8+j]; B: B[n=lane&15][k=quad*8+j]; D: col=lane&15,row=quad*4+reg
__global__ __launch_bounds__(256) void k_feat_mfma(const ushort16* __restrict__ xb,
    const ushort16* __restrict__ w1t, ushort16* __restrict__ feat1b) {
  int t = threadIdx.x, w = t >> 6, lane = t & 63;
  int quad = lane >> 4, m = lane & 15;
  int n0 = blockIdx.x * 16;
  const bf8v* ax = (const bf8v*)(xb + (n0 + m) * 64 + quad * 8);
  bf8v a0 = ax[0];        // k = quad*8 .. +7
  bf8v a1 = ax[4];        // k + 32
  int col_base = w * 64;
#pragma unroll
  for (int nt = 0; nt < 4; ++nt) {
    int colg = col_base + nt * 16 + m;
    const bf8v* bw = (const bf8v*)(w1t + colg * 64 + quad * 8);
    bf8v b0 = bw[0];
    bf8v b1 = bw[4];
    f32x4 acc = {0.f, 0.f, 0.f, 0.f};
    acc = __builtin_amdgcn_mfma_f32_16x16x32_bf16(a0, b0, acc, 0, 0, 0);
    acc = __builtin_amdgcn_mfma_f32_16x16x32_bf16(a1, b1, acc, 0, 0, 0);
#pragma unroll
    for (int i = 0; i < 4; ++i) {
      int row = quad * 4 + i;
      feat1b[(n0 + row) * 256 + colg] = f2bf(acc[i]);
    }
  }
}

// ---- el1/er1 from feat1b: 2 nodes/block, 128 thr/node, 2 elems/thr ----
__global__ __launch_bounds__(256) void k_el_er(const uint32* __restrict__ f2v,
    const float* __restrict__ al1, const float* __restrict__ ar1,
    float* __restrict__ el1, float* __restrict__ er1) {
  int t = threadIdx.x, tt = t & 127, nl = t >> 7;
  int n = blockIdx.x * 2 + nl;
  uint32 u = f2v[n * 128 + tt];
  float f0 = __uint_as_float(u << 16);
  float f1 = __uint_as_float(u & 0xffff0000u);
  int o = tt * 2;
  float pl = f0 * al1[o] + f1 * al1[o + 1];
  float pr = f0 * ar1[o] + f1 * ar1[o + 1];
#pragma unroll
  for (int off = 8; off > 0; off >>= 1) {
    pl += __shfl_down(pl, off, 16);
    pr += __shfl_down(pr, off, 16);
  }
  if ((tt & 15) == 0) {
    el1[n * 8 + (tt >> 4)] = pl;
    er1[n * 8 + (tt >> 4)] = pr;
  }
}

// ---- layer-1 aggregation: 8 nodes/block, 32 thr/node, 16B gathers, unroll-2,
// fused softmax + ReLU + b1 + W2 epilogue ----
__global__ __launch_bounds__(256) void k_agg1(const int* __restrict__ row_ptr,
    const int* __restrict__ esrc, const uint4* __restrict__ feat4,
    const float* __restrict__ el1, const float* __restrict__ er1,
    const float* __restrict__ b1, const float* __restrict__ W2,
    const float* __restrict__ al2, const float* __restrict__ ar2,
    float* __restrict__ feat2, float* __restrict__ el2, float* __restrict__ er2) {
  int t = threadIdx.x, nl = t >> 5, lt = t & 31;
  int n = blockIdx.x * 8 + nl;
  int h = lt >> 2;  // elements 8lt..8lt+7 all in head (8lt)>>5
  int begin = row_ptr[n], end = row_ptr[n + 1];
  float er_h = er1[n * 8 + h];
  float acc[8] = {0.f, 0.f, 0.f, 0.f, 0.f, 0.f, 0.f, 0.f};
  float s = 0.f;
  int e = begin;
  for (; e + 2 <= end; e += 2) {
    int sA = esrc[e], sB = esrc[e + 1];
    uint4 uA = feat4[sA * 32 + lt];
    uint4 uB = feat4[sB * 32 + lt];
    float vA = el1[sA * 8 + h] + er_h;
    float vB = el1[sB * 8 + h] + er_h;
    vA = vA > 0.f ? vA : 0.2f * vA;
    vB = vB > 0.f ? vB : 0.2f * vB;
    float exA = __expf(vA), exB = __expf(vB);
    s += exA + exB;
    uint32 ua[4] = {uA.x, uA.y, uA.z, uA.w};
    uint32 ub[4] = {uB.x, uB.y, uB.z, uB.w};
#pragma unroll
    for (int p = 0; p < 4; ++p) {
      acc[2 * p]     += __uint_as_float(ua[p] << 16) * exA + __uint_as_float(ub[p] << 16) * exB;
      acc[2 * p + 1] += __uint_as_float(ua[p] & 0xffff0000u) * exA +
                        __uint_as_float(ub[p] & 0xffff0000u) * exB;
    }
  }
  if (e < end) {
    int sA = esrc[e];
    uint4 uA = feat4[sA * 32 + lt];
    float vA = el1[sA * 8 + h] + er_h;
    vA = vA > 0.f ? vA : 0.2f * vA;
    float exA = __expf(vA);
    s += exA;
    uint32 ua[4] = {uA.x, uA.y, uA.z, uA.w};
#pragma unroll
    for (int p = 0; p < 4; ++p) {
      acc[2 * p]     += __uint_as_float(ua[p] << 16) * exA;
      acc[2 * p + 1] += __uint_as_float(ua[p] & 0xffff0000u) * exA;
    }
  }
  float inv = (end > begin) ? 1.f / s : 0.f;
  int o = lt * 8;
  float4 bb0 = *(const float4*)(b1 + o), bb1 = *(const float4*)(b1 + o + 4);
  float4 ww0 = *(const float4*)(W2 + o), ww1 = *(const float4*)(W2 + o + 4);
  float r = fmaxf(acc[0] * inv + bb0.x, 0.f) * ww0.x
          + fmaxf(acc[1] * inv + bb0.y, 0.f) * ww0.y
          + fmaxf(acc[2] * inv + bb0.z, 0.f) * ww0.z
          + fmaxf(acc[3] * inv + bb0.w, 0.f) * ww0.w
          + fmaxf(acc[4] * inv + bb1.x, 0.f) * ww1.x
          + fmaxf(acc[5] * inv + bb1.y, 0.f) * ww1.y
          + fmaxf(acc[6] * inv + bb1.z, 0.f) * ww1.z
          + fmaxf(acc[7] * inv + bb1.w, 0.f) * ww1.w;
  __shared__ float red[256];
  red[t] = r;
  __syncthreads();
  for (int off = 16; off > 0; off >>= 1) {
    if (lt < off) red[t] += red[t + off];
    __syncthreads();
  }
  if (lt == 0) {
    float f = red[t];
    feat2[n] = f;
    el2[n] = f * al2[0];
    er2[n] = f * ar2[0];
  }
}

// ---- layer-2 fused: 16 nodes/block, 16 thr/node, shfl-16 reduce, sigmoid ----
__global__ __launch_bounds__(256) void k_layer2(const int* __restrict__ row_ptr,
    const int* __restrict__ esrc, const float* __restrict__ feat2,
    const float* __restrict__ el2, const float* __restrict__ er2,
    const float* __restrict__ b2, float* __restrict__ out) {
  int t = threadIdx.x, g = t >> 4, lt = t & 15;
  int n = blockIdx.x * 16 + g;
  int begin = row_ptr[n], end = row_ptr[n + 1];
  float er_n = er2[n];
  float num = 0.f, s = 0.f;
  for (int e = begin + lt; e < end; e += 16) {
    int sN = esrc[e];
    float v = el2[sN] + er_n;
    v = v > 0.f ? v : 0.2f * v;
    float ex = __expf(v);
    num += feat2[sN] * ex;
    s += ex;
  }
#pragma unroll
  for (int off = 8; off > 0; off >>= 1) {
    num += __shfl_down(num, off, 16);
    s += __shfl_down(s, off, 16);
  }
  if (lt == 0) {
    float val = (end > begin) ? num / s : 0.f;
    out[n] = 1.f / (1.f + __expf(-(val + b2[0])));
  }
}

extern "C" void kernel_launch(void* const* d_in, const int* in_sizes, int n_in,
                              void* d_out, int out_size, void* d_ws, size_t ws_size,
                              hipStream_t stream) {
  const float* x   = (const float*)d_in[0];
  const int* src   = (const int*)d_in[1];
  const int* dst   = (const int*)d_in[2];
  // d_in[3] = edge_types (unused by reference)
  const float* W1  = (const float*)d_in[4];
  const float* al1 = (const float*)d_in[5];
  const float* ar1 = (const float*)d_in[6];
  const float* b1  = (const float*)d_in[7];
  const float* W2  = (const float*)d_in[8];
  const float* al2 = (const float*)d_in[9];
  const float* ar2 = (const float*)d_in[10];
  const float* b2  = (const float*)d_in[11];

  // Workspace (~39.6 MB), offsets in 4-byte words; 16B-aligned segments.
  // NOTE round-8 bug: w1t is 16,384 bf16 = 8,192 WORDS (ends 3,508,196);
  // feat1b must start after it. 3,508,200 is 16B-aligned.
  float* ws    = (float*)d_ws;
  float* el1   = ws;                       //   400,000 f
  float* er1   = ws + 400000;              //   400,000 f
  float* feat2 = ws + 800000;              //    50,000 f
  float* el2   = ws + 850000;              //    50,000 f
  float* er2   = ws + 900000;              //    50,000 f
  int* row_ptr = (int*)ws + 950000;        //    50,001 i (+pad to 50,004)
  int* deg     = (int*)ws + 1000004;       //    50,000 i (zero-init)
  int* cursor  = (int*)ws + 1050004;       //    50,000 i
  int* esrc    = (int*)ws + 1100004;       //   800,000 i
  ushort16* xb     = (ushort16*)((int*)ws + 1900004);  // 3,200,000 bf16 -> ends word 3,500,004
  ushort16* w1t    = (ushort16*)((int*)ws + 3500004);  //    16,384 bf16 -> ends word 3,508,196
  ushort16* feat1b = (ushort16*)((int*)ws + 3508200);  // 12,800,000 bf16 -> ends word 9,908,200

  hipMemsetAsync(deg, 0, 50000 * sizeof(int), stream);

  k_deg<<<N_EDGES / 256, 256, 0, stream>>>(dst, deg);
  k_scan<<<1, 1024, 0, stream>>>(deg, row_ptr, cursor);
  k_scatter<<<N_EDGES / 256, 256, 0, stream>>>(src, dst, cursor, esrc);
  k_cvt_x<<<(N_NODES * 64) / 1024, 256, 0, stream>>>(x, xb);
  k_cvt_w1t<<<1, 256, 0, stream>>>(W1, w1t);
  k_feat_mfma<<<N_NODES / 16, 256, 0, stream>>>(xb, w1t, feat1b);
  k_el_er<<<N_NODES / 2, 256, 0, stream>>>((const uint32*)feat1b, al1, ar1, el1, er1);
  k_agg1<<<N_NODES / 8, 256, 0, stream>>>(row_ptr, esrc, (const uint4*)feat1b,
                                          el1, er1, b1, W2, al2, ar2, feat2, el2, er2);
  k_layer2<<<N_NODES / 16, 256, 0, stream>>>(row_ptr, esrc, feat2, el2, er2, b2,
                                             (float*)d_out);
}

// Round 10
// 305.956 us; speedup vs baseline: 3.3027x; 1.3449x over previous
//
#include <hip/hip_runtime.h>

#define N_NODES 50000
#define N_EDGES 800000

typedef unsigned int uint32;
typedef unsigned short ushort16;
typedef short bf8v __attribute__((ext_vector_type(8)));   // 8 bf16 (4 VGPRs)
typedef float f32x4 __attribute__((ext_vector_type(4)));

// fp32 -> bf16 bits, round-to-nearest-even (identity on bf16-grid values)
__device__ __forceinline__ ushort16 f2bf(float f) {
  uint32 u = __float_as_uint(f);
  u += 0x7fffu + ((u >> 16) & 1u);
  return (ushort16)(u >> 16);
}

// ---- CSR construction ----
__global__ __launch_bounds__(256) void k_deg(const int* __restrict__ dst, int* __restrict__ deg) {
  int e = blockIdx.x * 256 + threadIdx.x;
  if (e < N_EDGES) atomicAdd(&deg[dst[e]], 1);
}

// Wave-atomic group allocator: replaces the serial scan. Group order = arbitrary
// (segment-sum is commutative, so order is irrelevant). 782 atomics total.
__global__ __launch_bounds__(256) void k_alloc(const int* __restrict__ deg,
    int* __restrict__ counter, int* __restrict__ row_ptr, int* __restrict__ cursor) {
  int n = blockIdx.x * 256 + threadIdx.x;
  int lane = threadIdx.x & 63;
  int d = (n < N_NODES) ? deg[n] : 0;
  int pre = d;  // inclusive prefix within wave
#pragma unroll
  for (int off = 1; off < 64; off <<= 1) {
    int v = __shfl_up(pre, off, 64);
    if (lane >= off) pre += v;
  }
  int excl = pre - d;
  int wsum = __shfl(pre, 63, 64);
  int base = 0;
  if (lane == 63) base = atomicAdd(counter, wsum);
  base = __shfl(base, 63, 64);
  if (n < N_NODES) {
    row_ptr[n] = base + excl;
    cursor[n] = base + excl;
  }
}

__global__ __launch_bounds__(256) void k_scatter(const int* __restrict__ src,
    const int* __restrict__ dst, int* __restrict__ cursor, int* __restrict__ esrc) {
  int e = blockIdx.x * 256 + threadIdx.x;
  if (e < N_EDGES) {
    int p = atomicAdd(&cursor[dst[e]], 1);
    esrc[p] = src[e];
  }
}

// ---- x (fp32, bf16-grid) -> bf16 bits; 4 elems/thread ----
__global__ __launch_bounds__(256) void k_cvt_x(const float* __restrict__ x,
    ushort16* __restrict__ xb) {
  int i = (blockIdx.x * 256 + threadIdx.x) * 4;
  float4 v = *(const float4*)(x + i);
  uint32 lo = (uint32)f2bf(v.x) | ((uint32)f2bf(v.y) << 16);
  uint32 hi = (uint32)f2bf(v.z) | ((uint32)f2bf(v.w) << 16);
  *(uint2*)(xb + i) = make_uint2(lo, hi);
}

// ---- W1[64][256] -> W1T bf16 [256][64] ----
__global__ __launch_bounds__(256) void k_cvt_w1t(const float* __restrict__ W1,
    ushort16* __restrict__ w1t) {
  int t = threadIdx.x;  // = column
  for (int k = 0; k < 64; ++k) w1t[t * 64 + k] = f2bf(W1[k * 256 + t]);
}

// ---- feat1b = x @ W1 via MFMA 16x16x32 bf16. Block: 16 nodes x 256 cols, 4 waves.
__global__ __launch_bounds__(256) void k_feat_mfma(const ushort16* __restrict__ xb,
    const ushort16* __restrict__ w1t, ushort16* __restrict__ feat1b) {
  int t = threadIdx.x, w = t >> 6, lane = t & 63;
  int quad = lane >> 4, m = lane & 15;
  int n0 = blockIdx.x * 16;
  const bf8v* ax = (const bf8v*)(xb + (n0 + m) * 64 + quad * 8);
  bf8v a0 = ax[0];        // k = quad*8 .. +7
  bf8v a1 = ax[4];        // k + 32
  int col_base = w * 64;
#pragma unroll
  for (int nt = 0; nt < 4; ++nt) {
    int colg = col_base + nt * 16 + m;
    const bf8v* bw = (const bf8v*)(w1t + colg * 64 + quad * 8);
    bf8v b0 = bw[0];
    bf8v b1 = bw[4];
    f32x4 acc = {0.f, 0.f, 0.f, 0.f};
    acc = __builtin_amdgcn_mfma_f32_16x16x32_bf16(a0, b0, acc, 0, 0, 0);
    acc = __builtin_amdgcn_mfma_f32_16x16x32_bf16(a1, b1, acc, 0, 0, 0);
#pragma unroll
    for (int i = 0; i < 4; ++i) {
      int row = quad * 4 + i;
      feat1b[(n0 + row) * 256 + colg] = f2bf(acc[i]);
    }
  }
}

// ---- el1/er1 from feat1b: 2 nodes/block, 128 thr/node, 2 elems/thr ----
__global__ __launch_bounds__(256) void k_el_er(const uint32* __restrict__ f2v,
    const float* __restrict__ al1, const float* __restrict__ ar1,
    float* __restrict__ el1, float* __restrict__ er1) {
  int t = threadIdx.x, tt = t & 127, nl = t >> 7;
  int n = blockIdx.x * 2 + nl;
  uint32 u = f2v[n * 128 + tt];
  float f0 = __uint_as_float(u << 16);
  float f1 = __uint_as_float(u & 0xffff0000u);
  int o = tt * 2;
  float pl = f0 * al1[o] + f1 * al1[o + 1];
  float pr = f0 * ar1[o] + f1 * ar1[o + 1];
#pragma unroll
  for (int off = 8; off > 0; off >>= 1) {
    pl += __shfl_down(pl, off, 16);
    pr += __shfl_down(pr, off, 16);
  }
  if ((tt & 15) == 0) {
    el1[n * 8 + (tt >> 4)] = pl;
    er1[n * 8 + (tt >> 4)] = pr;
  }
}

// ---- layer-1 aggregation: 8 nodes/block, 32 thr/node, 16B gathers, unroll-2,
// fused softmax + ReLU + b1 + W2 epilogue. end = begin + deg[n]. ----
__global__ __launch_bounds__(256) void k_agg1(const int* __restrict__ row_ptr,
    const int* __restrict__ deg, const int* __restrict__ esrc,
    const uint4* __restrict__ feat4,
    const float* __restrict__ el1, const float* __restrict__ er1,
    const float* __restrict__ b1, const float* __restrict__ W2,
    const float* __restrict__ al2, const float* __restrict__ ar2,
    float* __restrict__ feat2, float* __restrict__ el2, float* __restrict__ er2) {
  int t = threadIdx.x, nl = t >> 5, lt = t & 31;
  int n = blockIdx.x * 8 + nl;
  int h = lt >> 2;  // elements 8lt..8lt+7 all in head (8lt)>>5
  int begin = row_ptr[n], end = begin + deg[n];
  float er_h = er1[n * 8 + h];
  float acc[8] = {0.f, 0.f, 0.f, 0.f, 0.f, 0.f, 0.f, 0.f};
  float s = 0.f;
  int e = begin;
  for (; e + 2 <= end; e += 2) {
    int sA = esrc[e], sB = esrc[e + 1];
    uint4 uA = feat4[sA * 32 + lt];
    uint4 uB = feat4[sB * 32 + lt];
    float vA = el1[sA * 8 + h] + er_h;
    float vB = el1[sB * 8 + h] + er_h;
    vA = vA > 0.f ? vA : 0.2f * vA;
    vB = vB > 0.f ? vB : 0.2f * vB;
    float exA = __expf(vA), exB = __expf(vB);
    s += exA + exB;
    uint32 ua[4] = {uA.x, uA.y, uA.z, uA.w};
    uint32 ub[4] = {uB.x, uB.y, uB.z, uB.w};
#pragma unroll
    for (int p = 0; p < 4; ++p) {
      acc[2 * p]     += __uint_as_float(ua[p] << 16) * exA + __uint_as_float(ub[p] << 16) * exB;
      acc[2 * p + 1] += __uint_as_float(ua[p] & 0xffff0000u) * exA +
                        __uint_as_float(ub[p] & 0xffff0000u) * exB;
    }
  }
  if (e < end) {
    int sA = esrc[e];
    uint4 uA = feat4[sA * 32 + lt];
    float vA = el1[sA * 8 + h] + er_h;
    vA = vA > 0.f ? vA : 0.2f * vA;
    float exA = __expf(vA);
    s += exA;
    uint32 ua[4] = {uA.x, uA.y, uA.z, uA.w};
#pragma unroll
    for (int p = 0; p < 4; ++p) {
      acc[2 * p]     += __uint_as_float(ua[p] << 16) * exA;
      acc[2 * p + 1] += __uint_as_float(ua[p] & 0xffff0000u) * exA;
    }
  }
  float inv = (end > begin) ? 1.f / s : 0.f;
  int o = lt * 8;
  float4 bb0 = *(const float4*)(b1 + o), bb1 = *(const float4*)(b1 + o + 4);
  float4 ww0 = *(const float4*)(W2 + o), ww1 = *(const float4*)(W2 + o + 4);
  float r = fmaxf(acc[0] * inv + bb0.x, 0.f) * ww0.x
          + fmaxf(acc[1] * inv + bb0.y, 0.f) * ww0.y
          + fmaxf(acc[2] * inv + bb0.z, 0.f) * ww0.z
          + fmaxf(acc[3] * inv + bb0.w, 0.f) * ww0.w
          + fmaxf(acc[4] * inv + bb1.x, 0.f) * ww1.x
          + fmaxf(acc[5] * inv + bb1.y, 0.f) * ww1.y
          + fmaxf(acc[6] * inv + bb1.z, 0.f) * ww1.z
          + fmaxf(acc[7] * inv + bb1.w, 0.f) * ww1.w;
  __shared__ float red[256];
  red[t] = r;
  __syncthreads();
  for (int off = 16; off > 0; off >>= 1) {
    if (lt < off) red[t] += red[t + off];
    __syncthreads();
  }
  if (lt == 0) {
    float f = red[t];
    feat2[n] = f;
    el2[n] = f * al2[0];
    er2[n] = f * ar2[0];
  }
}

// ---- layer-2 fused: 16 nodes/block, 16 thr/node, shfl-16 reduce, sigmoid ----
__global__ __launch_bounds__(256) void k_layer2(const int* __restrict__ row_ptr,
    const int* __restrict__ deg, const int* __restrict__ esrc,
    const float* __restrict__ feat2,
    const float* __restrict__ el2, const float* __restrict__ er2,
    const float* __restrict__ b2, float* __restrict__ out) {
  int t = threadIdx.x, g = t >> 4, lt = t & 15;
  int n = blockIdx.x * 16 + g;
  int begin = row_ptr[n], end = begin + deg[n];
  float er_n = er2[n];
  float num = 0.f, s = 0.f;
  for (int e = begin + lt; e < end; e += 16) {
    int sN = esrc[e];
    float v = el2[sN] + er_n;
    v = v > 0.f ? v : 0.2f * v;
    float ex = __expf(v);
    num += feat2[sN] * ex;
    s += ex;
  }
#pragma unroll
  for (int off = 8; off > 0; off >>= 1) {
    num += __shfl_down(num, off, 16);
    s += __shfl_down(s, off, 16);
  }
  if (lt == 0) {
    float val = (end > begin) ? num / s : 0.f;
    out[n] = 1.f / (1.f + __expf(-(val + b2[0])));
  }
}

extern "C" void kernel_launch(void* const* d_in, const int* in_sizes, int n_in,
                              void* d_out, int out_size, void* d_ws, size_t ws_size,
                              hipStream_t stream) {
  const float* x   = (const float*)d_in[0];
  const int* src   = (const int*)d_in[1];
  const int* dst   = (const int*)d_in[2];
  // d_in[3] = edge_types (unused by reference)
  const float* W1  = (const float*)d_in[4];
  const float* al1 = (const float*)d_in[5];
  const float* ar1 = (const float*)d_in[6];
  const float* b1  = (const float*)d_in[7];
  const float* W2  = (const float*)d_in[8];
  const float* al2 = (const float*)d_in[9];
  const float* ar2 = (const float*)d_in[10];
  const float* b2  = (const float*)d_in[11];

  // Workspace (~39.6 MB), offsets in 4-byte words; 16B-aligned segments.
  float* ws    = (float*)d_ws;
  float* el1   = ws;                       //   400,000 f
  float* er1   = ws + 400000;              //   400,000 f
  float* feat2 = ws + 800000;              //    50,000 f
  float* el2   = ws + 850000;              //    50,000 f
  float* er2   = ws + 900000;              //    50,000 f
  int* row_ptr = (int*)ws + 950000;        //    50,000 i
  int* deg     = (int*)ws + 1000000;       //    50,000 i (zero-init)
  int* counter = (int*)ws + 1050000;       //         4 i (zero-init, padded)
  int* cursor  = (int*)ws + 1050004;       //    50,000 i
  int* esrc    = (int*)ws + 1100004;       //   800,000 i
  ushort16* xb     = (ushort16*)((int*)ws + 1900004);  // 3,200,000 bf16 -> ends word 3,500,004
  ushort16* w1t    = (ushort16*)((int*)ws + 3500004);  //    16,384 bf16 -> ends word 3,508,196
  ushort16* feat1b = (ushort16*)((int*)ws + 3508200);  // 12,800,000 bf16 -> ends word 9,908,200

  // zero deg + counter in one memset (contiguous)
  hipMemsetAsync(deg, 0, 50004 * sizeof(int), stream);

  k_deg<<<N_EDGES / 256, 256, 0, stream>>>(dst, deg);
  k_alloc<<<(N_NODES + 255) / 256, 256, 0, stream>>>(deg, counter, row_ptr, cursor);
  k_scatter<<<N_EDGES / 256, 256, 0, stream>>>(src, dst, cursor, esrc);
  k_cvt_x<<<(N_NODES * 64) / 1024, 256, 0, stream>>>(x, xb);
  k_cvt_w1t<<<1, 256, 0, stream>>>(W1, w1t);
  k_feat_mfma<<<N_NODES / 16, 256, 0, stream>>>(xb, w1t, feat1b);
  k_el_er<<<N_NODES / 2, 256, 0, stream>>>((const uint32*)feat1b, al1, ar1, el1, er1);
  k_agg1<<<N_NODES / 8, 256, 0, stream>>>(row_ptr, deg, esrc, (const uint4*)feat1b,
                                          el1, er1, b1, W2, al2, ar2, feat2, el2, er2);
  k_layer2<<<N_NODES / 16, 256, 0, stream>>>(row_ptr, deg, esrc, feat2, el2, er2, b2,
                                             (float*)d_out);
}

// Round 11
// 283.840 us; speedup vs baseline: 3.5601x; 1.0779x over previous
//
#include <hip/hip_runtime.h>

#define N_NODES 50000
#define N_EDGES 800000

typedef unsigned int uint32;
typedef unsigned short ushort16;
typedef short bf8v __attribute__((ext_vector_type(8)));   // 8 bf16 (4 VGPRs)
typedef float f32x4 __attribute__((ext_vector_type(4)));

// fp32 -> bf16 bits, round-to-nearest-even (identity on bf16-grid values)
__device__ __forceinline__ ushort16 f2bf(float f) {
  uint32 u = __float_as_uint(f);
  u += 0x7fffu + ((u >> 16) & 1u);
  return (ushort16)(u >> 16);
}

// ---- CSR construction ----
__global__ __launch_bounds__(256) void k_deg(const int* __restrict__ dst, int* __restrict__ deg) {
  int e = blockIdx.x * 256 + threadIdx.x;
  if (e < N_EDGES) atomicAdd(&deg[dst[e]], 1);
}

// Wave-atomic group allocator (group order arbitrary; segment-sum commutes).
__global__ __launch_bounds__(256) void k_alloc(const int* __restrict__ deg,
    int* __restrict__ counter, int* __restrict__ row_ptr, int* __restrict__ cursor) {
  int n = blockIdx.x * 256 + threadIdx.x;
  int lane = threadIdx.x & 63;
  int d = (n < N_NODES) ? deg[n] : 0;
  int pre = d;
#pragma unroll
  for (int off = 1; off < 64; off <<= 1) {
    int v = __shfl_up(pre, off, 64);
    if (lane >= off) pre += v;
  }
  int excl = pre - d;
  int wsum = __shfl(pre, 63, 64);
  int base = 0;
  if (lane == 63) base = atomicAdd(counter, wsum);
  base = __shfl(base, 63, 64);
  if (n < N_NODES) {
    row_ptr[n] = base + excl;
    cursor[n] = base + excl;
  }
}

__global__ __launch_bounds__(256) void k_scatter(const int* __restrict__ src,
    const int* __restrict__ dst, int* __restrict__ cursor, int* __restrict__ esrc) {
  int e = blockIdx.x * 256 + threadIdx.x;
  if (e < N_EDGES) {
    int p = atomicAdd(&cursor[dst[e]], 1);
    esrc[p] = src[e];
  }
}

// ---- W1[64][256] -> W1T bf16 [256][64], 64 blocks ----
__global__ __launch_bounds__(256) void k_cvt_w1t(const float* __restrict__ W1,
    ushort16* __restrict__ w1t) {
  int t = threadIdx.x;
  int col = blockIdx.x * 4 + (t >> 6), k = t & 63;
  w1t[col * 64 + k] = f2bf(W1[k * 256 + col]);
}

// ---- feat1b = x @ W1 via MFMA 16x16x32 bf16; fused x->bf16 convert and
// el1/er1 (each wave owns heads 2w,2w+1 completely -> quad xor-butterfly). ----
__global__ __launch_bounds__(256) void k_feat_mfma(const float* __restrict__ x,
    const ushort16* __restrict__ w1t, const float* __restrict__ al1,
    const float* __restrict__ ar1, ushort16* __restrict__ feat1b,
    float* __restrict__ el1, float* __restrict__ er1) {
  int t = threadIdx.x, w = t >> 6, lane = t & 63;
  int quad = lane >> 4, m = lane & 15;
  int n0 = blockIdx.x * 16;
  const float* xr = x + (n0 + m) * 64 + quad * 8;
  float4 xa = *(const float4*)(xr);
  float4 xbv = *(const float4*)(xr + 4);
  float4 xc = *(const float4*)(xr + 32);
  float4 xd = *(const float4*)(xr + 36);
  bf8v a0, a1;
  a0[0] = (short)f2bf(xa.x); a0[1] = (short)f2bf(xa.y);
  a0[2] = (short)f2bf(xa.z); a0[3] = (short)f2bf(xa.w);
  a0[4] = (short)f2bf(xbv.x); a0[5] = (short)f2bf(xbv.y);
  a0[6] = (short)f2bf(xbv.z); a0[7] = (short)f2bf(xbv.w);
  a1[0] = (short)f2bf(xc.x); a1[1] = (short)f2bf(xc.y);
  a1[2] = (short)f2bf(xc.z); a1[3] = (short)f2bf(xc.w);
  a1[4] = (short)f2bf(xd.x); a1[5] = (short)f2bf(xd.y);
  a1[6] = (short)f2bf(xd.z); a1[7] = (short)f2bf(xd.w);
  // partials: head 2w (nt 0,1) and head 2w+1 (nt 2,3), per row i
  float pl0[4] = {0.f, 0.f, 0.f, 0.f}, pr0[4] = {0.f, 0.f, 0.f, 0.f};
  float pl1[4] = {0.f, 0.f, 0.f, 0.f}, pr1[4] = {0.f, 0.f, 0.f, 0.f};
#pragma unroll
  for (int nt = 0; nt < 4; ++nt) {
    int colg = w * 64 + nt * 16 + m;
    const bf8v* bw = (const bf8v*)(w1t + colg * 64 + quad * 8);
    bf8v b0 = bw[0];
    bf8v b1 = bw[4];
    f32x4 acc = {0.f, 0.f, 0.f, 0.f};
    acc = __builtin_amdgcn_mfma_f32_16x16x32_bf16(a0, b0, acc, 0, 0, 0);
    acc = __builtin_amdgcn_mfma_f32_16x16x32_bf16(a1, b1, acc, 0, 0, 0);
    float al = al1[colg], ar = ar1[colg];
#pragma unroll
    for (int i = 0; i < 4; ++i) {
      feat1b[(n0 + quad * 4 + i) * 256 + colg] = f2bf(acc[i]);
      if (nt < 2) { pl0[i] += acc[i] * al; pr0[i] += acc[i] * ar; }
      else        { pl1[i] += acc[i] * al; pr1[i] += acc[i] * ar; }
    }
  }
#pragma unroll
  for (int off = 1; off < 16; off <<= 1) {
#pragma unroll
    for (int i = 0; i < 4; ++i) {
      pl0[i] += __shfl_xor(pl0[i], off, 64);
      pr0[i] += __shfl_xor(pr0[i], off, 64);
      pl1[i] += __shfl_xor(pl1[i], off, 64);
      pr1[i] += __shfl_xor(pr1[i], off, 64);
    }
  }
  if (m == 0) {
#pragma unroll
    for (int i = 0; i < 4; ++i) {
      int n = n0 + quad * 4 + i;
      el1[n * 8 + 2 * w] = pl0[i];
      er1[n * 8 + 2 * w] = pr0[i];
      el1[n * 8 + 2 * w + 1] = pl1[i];
      er1[n * 8 + 2 * w + 1] = pr1[i];
    }
  }
}

#define ACC8(u, ex)                                              \
  {                                                              \
    acc[0] += __uint_as_float((u).x << 16) * (ex);               \
    acc[1] += __uint_as_float((u).x & 0xffff0000u) * (ex);       \
    acc[2] += __uint_as_float((u).y << 16) * (ex);               \
    acc[3] += __uint_as_float((u).y & 0xffff0000u) * (ex);       \
    acc[4] += __uint_as_float((u).z << 16) * (ex);               \
    acc[5] += __uint_as_float((u).z & 0xffff0000u) * (ex);       \
    acc[6] += __uint_as_float((u).w << 16) * (ex);               \
    acc[7] += __uint_as_float((u).w & 0xffff0000u) * (ex);       \
  }

// ---- layer-1 aggregation: 8 nodes/block, 32 thr/node, 16B gathers, unroll-4,
// fused softmax + ReLU + b1 + W2 epilogue -> feat2 only ----
__global__ __launch_bounds__(256) void k_agg1(const int* __restrict__ row_ptr,
    const int* __restrict__ deg, const int* __restrict__ esrc,
    const uint4* __restrict__ feat4,
    const float* __restrict__ el1, const float* __restrict__ er1,
    const float* __restrict__ b1, const float* __restrict__ W2,
    float* __restrict__ feat2) {
  int t = threadIdx.x, nl = t >> 5, lt = t & 31;
  int n = blockIdx.x * 8 + nl;
  int h = lt >> 2;
  int begin = row_ptr[n], end = begin + deg[n];
  float er_h = er1[n * 8 + h];
  float acc[8] = {0.f, 0.f, 0.f, 0.f, 0.f, 0.f, 0.f, 0.f};
  float s = 0.f;
  int e = begin;
  for (; e + 4 <= end; e += 4) {
    int s0 = esrc[e], s1 = esrc[e + 1], s2 = esrc[e + 2], s3 = esrc[e + 3];
    uint4 u0 = feat4[s0 * 32 + lt];
    uint4 u1 = feat4[s1 * 32 + lt];
    uint4 u2 = feat4[s2 * 32 + lt];
    uint4 u3 = feat4[s3 * 32 + lt];
    float v0 = el1[s0 * 8 + h] + er_h;
    float v1 = el1[s1 * 8 + h] + er_h;
    float v2 = el1[s2 * 8 + h] + er_h;
    float v3 = el1[s3 * 8 + h] + er_h;
    v0 = v0 > 0.f ? v0 : 0.2f * v0;
    v1 = v1 > 0.f ? v1 : 0.2f * v1;
    v2 = v2 > 0.f ? v2 : 0.2f * v2;
    v3 = v3 > 0.f ? v3 : 0.2f * v3;
    float ex0 = __expf(v0), ex1 = __expf(v1), ex2 = __expf(v2), ex3 = __expf(v3);
    s += ex0 + ex1 + ex2 + ex3;
    ACC8(u0, ex0);
    ACC8(u1, ex1);
    ACC8(u2, ex2);
    ACC8(u3, ex3);
  }
  for (; e < end; ++e) {
    int s0 = esrc[e];
    uint4 u0 = feat4[s0 * 32 + lt];
    float v0 = el1[s0 * 8 + h] + er_h;
    v0 = v0 > 0.f ? v0 : 0.2f * v0;
    float ex0 = __expf(v0);
    s += ex0;
    ACC8(u0, ex0);
  }
  float inv = (end > begin) ? 1.f / s : 0.f;
  int o = lt * 8;
  float4 bb0 = *(const float4*)(b1 + o), bb1 = *(const float4*)(b1 + o + 4);
  float4 ww0 = *(const float4*)(W2 + o), ww1 = *(const float4*)(W2 + o + 4);
  float r = fmaxf(acc[0] * inv + bb0.x, 0.f) * ww0.x
          + fmaxf(acc[1] * inv + bb0.y, 0.f) * ww0.y
          + fmaxf(acc[2] * inv + bb0.z, 0.f) * ww0.z
          + fmaxf(acc[3] * inv + bb0.w, 0.f) * ww0.w
          + fmaxf(acc[4] * inv + bb1.x, 0.f) * ww1.x
          + fmaxf(acc[5] * inv + bb1.y, 0.f) * ww1.y
          + fmaxf(acc[6] * inv + bb1.z, 0.f) * ww1.z
          + fmaxf(acc[7] * inv + bb1.w, 0.f) * ww1.w;
  __shared__ float red[256];
  red[t] = r;
  __syncthreads();
  for (int off = 16; off > 0; off >>= 1) {
    if (lt < off) red[t] += red[t + off];
    __syncthreads();
  }
  if (lt == 0) feat2[n] = red[t];
}

// ---- layer-2 fused: el2/er2 = feat2 * scalar (computed on the fly; one gather
// per edge). 16 nodes/block, 16 thr/node, shfl-16 reduce, sigmoid. ----
__global__ __launch_bounds__(256) void k_layer2(const int* __restrict__ row_ptr,
    const int* __restrict__ deg, const int* __restrict__ esrc,
    const float* __restrict__ feat2, const float* __restrict__ al2,
    const float* __restrict__ ar2, const float* __restrict__ b2,
    float* __restrict__ out) {
  int t = threadIdx.x, g = t >> 4, lt = t & 15;
  int n = blockIdx.x * 16 + g;
  int begin = row_ptr[n], end = begin + deg[n];
  float a2 = al2[0];
  float er_n = feat2[n] * ar2[0];
  float num = 0.f, s = 0.f;
  for (int e = begin + lt; e < end; e += 16) {
    int sN = esrc[e];
    float f = feat2[sN];
    float v = f * a2 + er_n;
    v = v > 0.f ? v : 0.2f * v;
    float ex = __expf(v);
    num += f * ex;
    s += ex;
  }
#pragma unroll
  for (int off = 8; off > 0; off >>= 1) {
    num += __shfl_down(num, off, 16);
    s += __shfl_down(s, off, 16);
  }
  if (lt == 0) {
    float val = (end > begin) ? num / s : 0.f;
    out[n] = 1.f / (1.f + __expf(-(val + b2[0])));
  }
}

extern "C" void kernel_launch(void* const* d_in, const int* in_sizes, int n_in,
                              void* d_out, int out_size, void* d_ws, size_t ws_size,
                              hipStream_t stream) {
  const float* x   = (const float*)d_in[0];
  const int* src   = (const int*)d_in[1];
  const int* dst   = (const int*)d_in[2];
  // d_in[3] = edge_types (unused by reference)
  const float* W1  = (const float*)d_in[4];
  const float* al1 = (const float*)d_in[5];
  const float* ar1 = (const float*)d_in[6];
  const float* b1  = (const float*)d_in[7];
  const float* W2  = (const float*)d_in[8];
  const float* al2 = (const float*)d_in[9];
  const float* ar2 = (const float*)d_in[10];
  const float* b2  = (const float*)d_in[11];

  // Workspace (~32.8 MB), offsets in 4-byte words.
  float* ws    = (float*)d_ws;
  float* el1   = ws;                       //   400,000 f
  float* er1   = ws + 400000;              //   400,000 f
  float* feat2 = ws + 800000;              //    50,000 f
  int* row_ptr = (int*)ws + 850000;        //    50,000 i
  int* deg     = (int*)ws + 900000;        //    50,000 i (zero-init)
  int* counter = (int*)ws + 950000;        //         4 i (zero-init w/ deg)
  int* cursor  = (int*)ws + 950004;        //    50,000 i
  int* esrc    = (int*)ws + 1000004;       //   800,000 i
  ushort16* w1t    = (ushort16*)((int*)ws + 1800004);  //    16,384 bf16 -> ends word 1,808,196
  ushort16* feat1b = (ushort16*)((int*)ws + 1808200);  // 12,800,000 bf16 -> ends word 8,208,200

  hipMemsetAsync(deg, 0, 50004 * sizeof(int), stream);  // deg + counter (contiguous)

  k_deg<<<N_EDGES / 256, 256, 0, stream>>>(dst, deg);
  k_alloc<<<(N_NODES + 255) / 256, 256, 0, stream>>>(deg, counter, row_ptr, cursor);
  k_scatter<<<N_EDGES / 256, 256, 0, stream>>>(src, dst, cursor, esrc);
  k_cvt_w1t<<<64, 256, 0, stream>>>(W1, w1t);
  k_feat_mfma<<<N_NODES / 16, 256, 0, stream>>>(x, w1t, al1, ar1, feat1b, el1, er1);
  k_agg1<<<N_NODES / 8, 256, 0, stream>>>(row_ptr, deg, esrc, (const uint4*)feat1b,
                                          el1, er1, b1, W2, feat2);
  k_layer2<<<N_NODES / 16, 256, 0, stream>>>(row_ptr, deg, esrc, feat2, al2, ar2, b2,
                                             (float*)d_out);
}